// Round 16
// baseline (121.158 us; speedup 1.0000x reference)
//
#include <hip/hip_runtime.h>

typedef __fp16 h2 __attribute__((ext_vector_type(2)));
typedef float f4 __attribute__((ext_vector_type(4)));

static __device__ __forceinline__ unsigned pkrtz(float a, float b) {
    union { h2 v; unsigned u; } cv;
    cv.v = __builtin_amdgcn_cvt_pkrtz(a, b);
    return cv.u;
}
static __device__ __forceinline__ h2 as_h2(unsigned u) {
    union { unsigned u; h2 v; } cv; cv.u = u; return cv.v;
}

// ---- prep: pack weights into f16-pair dwords in d_ws -------------------------
//   [j*6 + i]      i<5 : (W1[j][2i], W1[j][2i+1]) f16 pair       (j in 0..39)
//   [j*6 + 5]          : b1[j] as f32 bits
//   [240 + p*4+o]      : (W2[o][2p], W2[o][2p+1]) f16 pair       (p in 0..19)
//   [320 + o]          : b2[o] as f32 bits
__global__ void prep_kernel(const float* __restrict__ W1, const float* __restrict__ b1,
                            const float* __restrict__ W2, const float* __restrict__ b2,
                            unsigned* __restrict__ ws) {
    const int t = threadIdx.x;
    if (t < 40) {
        #pragma unroll
        for (int i = 0; i < 5; ++i)
            ws[t * 6 + i] = pkrtz(W1[t * 10 + 2 * i], W1[t * 10 + 2 * i + 1]);
        ws[t * 6 + 5] = __float_as_uint(b1[t]);
    } else if (t < 60) {
        const int p = t - 40;
        #pragma unroll
        for (int o = 0; o < 4; ++o)
            ws[240 + p * 4 + o] = pkrtz(W2[o * 40 + 2 * p], W2[o * 40 + 2 * p + 1]);
    } else if (t < 64) {
        ws[320 + (t - 60)] = __float_as_uint(b2[t - 60]);
    }
}

// ---- main: grid-stride, 2-deep software pipeline -----------------------------
// While computing chunk i: chunk i+1's gathers + w and chunk i+2's indices are
// in flight. Named-register rotation (no runtime-indexed arrays).
#define TPB 256

__global__ __launch_bounds__(TPB) void edge_mlp_pipe_kernel(
    const float* __restrict__ x,
    const float* __restrict__ w,
    const int* __restrict__ src,
    const int* __restrict__ dst,
    const unsigned* __restrict__ W,   // packed weights (uniform -> SGPR/K$)
    float* __restrict__ w_out,
    float* __restrict__ e_tilde,
    int E, int S)
{
    __shared__ float s_et[4][64 * 7];   // per-wave staging (wave-local, no barrier)

    const int t    = threadIdx.x;
    const int wave = t >> 6;
    const int lane = t & 63;

    int eA = blockIdx.x * TPB + t;      // current chunk edge
    int eB = eA + S;                    // next chunk
    int eC = eB + S;                    // next-next (idx prefetch only)

    // --- prologue: idx for A and B; gathers + w for A ---
    int siB = 0, diB = 0;
    float a0 = 0.f, a1 = 0.f, a2 = 0.f, a3 = 0.f, a4 = 0.f, a5 = 0.f;
    f4 wvA = {0.f, 0.f, 0.f, 0.f};
    {
        int siA = 0, diA = 0;
        if (eA < E) {
            siA = __builtin_nontemporal_load(src + eA);
            diA = __builtin_nontemporal_load(dst + eA);
        }
        if (eB < E) {
            siB = __builtin_nontemporal_load(src + eB);
            diB = __builtin_nontemporal_load(dst + eB);
        }
        if (eA < E) {
            a0 = x[3 * siA]; a1 = x[3 * siA + 1]; a2 = x[3 * siA + 2];
            a3 = x[3 * diA]; a4 = x[3 * diA + 1]; a5 = x[3 * diA + 2];
            wvA = __builtin_nontemporal_load((const f4*)w + eA);
        }
    }

    for (int base = blockIdx.x * TPB; base < E; base += S) {
        // --- prefetch: B gathers + w, C indices (independent of compute) ---
        float b0 = 0.f, b1v = 0.f, b2v = 0.f, b3 = 0.f, b4 = 0.f, b5 = 0.f;
        f4 wvB = {0.f, 0.f, 0.f, 0.f};
        if (eB < E) {
            b0 = x[3 * siB]; b1v = x[3 * siB + 1]; b2v = x[3 * siB + 2];
            b3 = x[3 * diB]; b4 = x[3 * diB + 1]; b5 = x[3 * diB + 2];
            wvB = __builtin_nontemporal_load((const f4*)w + eB);
        }
        int siC = 0, diC = 0;
        if (eC < E) {
            siC = __builtin_nontemporal_load(src + eC);
            diC = __builtin_nontemporal_load(dst + eC);
        }

        // --- compute chunk A ---
        const h2 vm0 = as_h2(pkrtz(a0, a1));
        const h2 vm1 = as_h2(pkrtz(a2, a3));
        const h2 vm2 = as_h2(pkrtz(a4, a5));
        const h2 vm3 = as_h2(pkrtz(wvA.x, wvA.y));
        const h2 vm4 = as_h2(pkrtz(wvA.z, wvA.w));

        float o0 = __uint_as_float(W[320]);
        float o1 = __uint_as_float(W[321]);
        float o2 = __uint_as_float(W[322]);
        float o3 = __uint_as_float(W[323]);

        #pragma unroll
        for (int jp = 0; jp < 20; ++jp) {
            const int j0 = 2 * jp, j1 = 2 * jp + 1;
            float h0v = __uint_as_float(W[j0 * 6 + 5]);
            float h1v = __uint_as_float(W[j1 * 6 + 5]);
            h0v = __builtin_amdgcn_fdot2(vm0, as_h2(W[j0 * 6 + 0]), h0v, false);
            h1v = __builtin_amdgcn_fdot2(vm0, as_h2(W[j1 * 6 + 0]), h1v, false);
            h0v = __builtin_amdgcn_fdot2(vm1, as_h2(W[j0 * 6 + 1]), h0v, false);
            h1v = __builtin_amdgcn_fdot2(vm1, as_h2(W[j1 * 6 + 1]), h1v, false);
            h0v = __builtin_amdgcn_fdot2(vm2, as_h2(W[j0 * 6 + 2]), h0v, false);
            h1v = __builtin_amdgcn_fdot2(vm2, as_h2(W[j1 * 6 + 2]), h1v, false);
            h0v = __builtin_amdgcn_fdot2(vm3, as_h2(W[j0 * 6 + 3]), h0v, false);
            h1v = __builtin_amdgcn_fdot2(vm3, as_h2(W[j1 * 6 + 3]), h1v, false);
            h0v = __builtin_amdgcn_fdot2(vm4, as_h2(W[j0 * 6 + 4]), h0v, false);
            h1v = __builtin_amdgcn_fdot2(vm4, as_h2(W[j1 * 6 + 4]), h1v, false);
            h0v = fmaxf(h0v, 0.f);
            h1v = fmaxf(h1v, 0.f);
            const h2 hp = as_h2(pkrtz(h0v, h1v));
            o0 = __builtin_amdgcn_fdot2(hp, as_h2(W[240 + jp * 4 + 0]), o0, false);
            o1 = __builtin_amdgcn_fdot2(hp, as_h2(W[240 + jp * 4 + 1]), o1, false);
            o2 = __builtin_amdgcn_fdot2(hp, as_h2(W[240 + jp * 4 + 2]), o2, false);
            o3 = __builtin_amdgcn_fdot2(hp, as_h2(W[240 + jp * 4 + 3]), o3, false);
        }

        const int e = base + t;
        if (e < E) {
            f4 ov; ov.x = o0; ov.y = o1; ov.z = o2; ov.w = o3;
            __builtin_nontemporal_store(ov, (f4*)w_out + e);
        }

        // e_tilde: wave-local LDS exchange, then coalesced f4 nt stores
        float* sw = s_et[wave];
        sw[lane * 7 + 0] = a0;
        sw[lane * 7 + 1] = a1;
        sw[lane * 7 + 2] = a2;
        sw[lane * 7 + 3] = o0;
        sw[lane * 7 + 4] = o1;
        sw[lane * 7 + 5] = o2;
        sw[lane * 7 + 6] = o3;

        const int base_e = base + wave * 64;
        const long long fbase = (long long)base_e * 7;
        if (base_e + 64 <= E) {
            f4* dst4 = (f4*)(e_tilde + fbase);
            {
                f4 v0; v0.x = sw[4 * lane]; v0.y = sw[4 * lane + 1];
                v0.z = sw[4 * lane + 2]; v0.w = sw[4 * lane + 3];
                __builtin_nontemporal_store(v0, dst4 + lane);
            }
            if (lane < 48) {
                const int i2 = 64 + lane;
                f4 v1; v1.x = sw[4 * i2]; v1.y = sw[4 * i2 + 1];
                v1.z = sw[4 * i2 + 2]; v1.w = sw[4 * i2 + 3];
                __builtin_nontemporal_store(v1, dst4 + i2);
            }
        } else if (base_e < E) {
            const int nvalid = (E - base_e) * 7;
            #pragma unroll
            for (int k = 0; k < 7; ++k) {
                const int idx = lane + 64 * k;
                if (idx < nvalid)
                    __builtin_nontemporal_store(sw[idx], e_tilde + fbase + idx);
            }
        }

        // --- rotate pipeline state ---
        a0 = b0; a1 = b1v; a2 = b2v; a3 = b3; a4 = b4; a5 = b5;
        wvA = wvB;
        siB = siC; diB = diC;
        eA = eB; eB = eC; eC += S;
    }
}

extern "C" void kernel_launch(void* const* d_in, const int* in_sizes, int n_in,
                              void* d_out, int out_size, void* d_ws, size_t ws_size,
                              hipStream_t stream) {
    const float* x  = (const float*)d_in[0];
    const float* w  = (const float*)d_in[1];
    const float* W1 = (const float*)d_in[2];
    const float* b1 = (const float*)d_in[3];
    const float* W2 = (const float*)d_in[4];
    const float* b2 = (const float*)d_in[5];
    const int* src  = (const int*)d_in[6];
    const int* dst  = (const int*)d_in[7];

    const int E = in_sizes[6];

    float* w_out   = (float*)d_out;
    float* e_tilde = w_out + (size_t)E * 4;
    unsigned* ws   = (unsigned*)d_ws;

    prep_kernel<<<1, 64, 0, stream>>>(W1, b1, W2, b2, ws);

    int nblocks = (E + TPB - 1) / TPB;
    if (nblocks > 2048) nblocks = 2048;
    const int S = nblocks * TPB;
    edge_mlp_pipe_kernel<<<nblocks, TPB, 0, stream>>>(
        x, w, src, dst, ws, w_out, e_tilde, E, S);
}